// Round 7
// baseline (83.347 us; speedup 1.0000x reference)
//
#include <hip/hip_runtime.h>
#include <hip/hip_bf16.h>

typedef __bf16 bf16_t;
typedef bf16_t bf16x4 __attribute__((ext_vector_type(4)));
typedef bf16_t bf16x8 __attribute__((ext_vector_type(8)));
typedef float  f32x4  __attribute__((ext_vector_type(4)));

constexpr int M_TOT = 65536;   // B*S
constexpr int N_TOT = 512;     // E
constexpr int K_TOT = 512;     // E
constexpr int BM = 128, BN = 128, BK = 64;
constexpr int NT = K_TOT / BK; // 8 K-tiles

__device__ inline void gload_lds16(const void* g, void* l) {
    __builtin_amdgcn_global_load_lds(
        (const __attribute__((address_space(1))) void*)g,
        (__attribute__((address_space(3))) void*)l, 16, 0, 0);
}

// W (f32 [N][K]) -> bf16, chunk-XOR-swizzled: main kernel global_load_lds's it
// LINEARLY, reads back with chunk XOR. Wws[n][kt*64+(ck^(n&7))*8+j]=bf16(W[n][kt*64+ck*8+j])
__global__ __launch_bounds__(256)
void convert_W(const float* __restrict__ W, bf16_t* __restrict__ Wws)
{
    const int g  = blockIdx.x * 256 + threadIdx.x;
    const int n  = g >> 6;
    const int c  = g & 63;
    const int kt = c >> 3, ck = c & 7;
    const float4* src = reinterpret_cast<const float4*>(W + (size_t)n * K_TOT + c * 8);
    float4 v0 = src[0], v1 = src[1];
    bf16x8 b;
    b[0] = (bf16_t)v0.x; b[1] = (bf16_t)v0.y; b[2] = (bf16_t)v0.z; b[3] = (bf16_t)v0.w;
    b[4] = (bf16_t)v1.x; b[5] = (bf16_t)v1.y; b[6] = (bf16_t)v1.z; b[7] = (bf16_t)v1.w;
    const int dc = kt * 64 + ((ck ^ (n & 7)) * 8);
    *reinterpret_cast<bf16x8*>(Wws + (size_t)n * K_TOT + dc) = b;
}

// out[m,n] = sum_k cos(x[m,k] + phi[k%8]) * W[n,k] + bias[n]
// Dual double-buffered (A and B), ONE barrier per K-step:
//   step t: issue B(t+1)->Bs[t^1] (4 gload_lds/wave) + x(t+2)->regs;
//           MFMA from As[t],Bs[t] with cos(x(t+1))->As[t^1] interleaved;
//           s_waitcnt vmcnt(8) lgkmcnt(0); s_barrier.
// vmcnt(8): B gloads issued BEFORE the 8 x-loads (sched_barrier pins order),
// so 8-newer == x stays in flight, B drained. LDS 64KB -> 2 blocks/CU;
// (256,2) -> 256-reg budget, no spill (R3 lesson: never over-ask occupancy).
template<bool USE_WS>
__global__ __launch_bounds__(256, 2)
void qattn_fused_gemm(const float* __restrict__ x,
                      const float* __restrict__ phi,
                      const float* __restrict__ W,
                      const bf16_t* __restrict__ Wws,
                      const float* __restrict__ bias,
                      float* __restrict__ out)
{
    __shared__ bf16_t As[2][BM][BK];   // 32 KB
    __shared__ bf16_t Bs[2][BN][BK];   // 32 KB

    const int tid  = threadIdx.x;
    const int lane = tid & 63;
    const int wave = tid >> 6;

    // XCD-bijective swizzle: 4 blocks sharing an x-panel on one XCD's L2.
    const int xcd = blockIdx.x & 7;
    const int idx = blockIdx.x >> 3;
    const int wid = xcd * 256 + idx;
    const int bm  = (wid >> 2) * BM;
    const int bn  = (wid & 3)  * BN;

    // A staging: 16 rows x 16 float4 per pass, 8 passes
    const int srow = tid >> 4;
    const int scol = (tid & 15) * 4;
    const int pbase = scol & 4;
    const float p0 = phi[pbase + 0];
    const float p1 = phi[pbase + 1];
    const float p2 = phi[pbase + 2];
    const float p3 = phi[pbase + 3];

    const int wm   = (wave >> 1) * 64;
    const int wn   = (wave & 1) * 64;
    const int frow = lane & 15;
    const int fk   = (lane >> 4) * 8;

    f32x4  acc[4][4] = {};
    float4 pa[2][8];   // x tiles in flight; indices static under full unroll

    const float* xb = x + (size_t)bm * K_TOT;

    // ================= prologue =================
    // B(0) gloads FIRST (oldest in vmcnt FIFO)
    if constexpr (USE_WS) {
        #pragma unroll
        for (int i = 0; i < 4; ++i) {
            const bf16_t* src = Wws + (size_t)(bn + wave * 32 + i * 8 + (lane >> 3)) * K_TOT
                                + (lane & 7) * 8;
            gload_lds16(src, &Bs[0][0][0] + wave * 2048 + i * 512);
        }
    } else {
        const int brow = tid >> 1;
        #pragma unroll
        for (int i = 0; i < 4; ++i) {
            const int ck = (tid & 1) * 4 + i;
            const float4* s = reinterpret_cast<const float4*>(
                W + (size_t)(bn + brow) * K_TOT + ck * 8);
            float4 v0 = s[0], v1 = s[1];
            bf16x8 b;
            b[0] = (bf16_t)v0.x; b[1] = (bf16_t)v0.y; b[2] = (bf16_t)v0.z; b[3] = (bf16_t)v0.w;
            b[4] = (bf16_t)v1.x; b[5] = (bf16_t)v1.y; b[6] = (bf16_t)v1.z; b[7] = (bf16_t)v1.w;
            *reinterpret_cast<bf16x8*>(&Bs[0][brow][(ck ^ (brow & 7)) * 8]) = b;
        }
    }
    __builtin_amdgcn_sched_barrier(0);
    // x(0), x(1)
    #pragma unroll
    for (int p = 0; p < 8; ++p)
        pa[0][p] = *reinterpret_cast<const float4*>(
            xb + (size_t)(srow + p * 16) * K_TOT + scol);
    #pragma unroll
    for (int p = 0; p < 8; ++p)
        pa[1][p] = *reinterpret_cast<const float4*>(
            xb + (size_t)(srow + p * 16) * K_TOT + BK + scol);
    // cos(x(0)) -> As[0]   (compiler waits x(0) only: x(1) stays in flight)
    #pragma unroll
    for (int p = 0; p < 8; ++p) {
        const int row = srow + p * 16;
        const int csw = scol ^ ((row & 7) << 3);
        bf16x4 a;
        a[0] = (bf16_t)__cosf(pa[0][p].x + p0);
        a[1] = (bf16_t)__cosf(pa[0][p].y + p1);
        a[2] = (bf16_t)__cosf(pa[0][p].z + p2);
        a[3] = (bf16_t)__cosf(pa[0][p].w + p3);
        *reinterpret_cast<bf16x4*>(&As[0][row][csw]) = a;
    }
    // drain B(0) (8 newer x(1) loads stay in flight) + my ds_writes
    if constexpr (USE_WS)
        asm volatile("s_waitcnt vmcnt(8) lgkmcnt(0)\n\ts_barrier" ::: "memory");
    else
        asm volatile("s_waitcnt lgkmcnt(0)\n\ts_barrier" ::: "memory");

    // ================= main loop (fully unrolled; t compile-time) =========
    #pragma unroll
    for (int t = 0; t < NT; ++t) {
        const int cur = t & 1;

        // ---- issue B(t+1) -> Bs[cur^1] (last read at step t-1; barrier passed) ----
        if (t < NT - 1) {
            if constexpr (USE_WS) {
                #pragma unroll
                for (int i = 0; i < 4; ++i) {
                    const bf16_t* src = Wws
                        + (size_t)(bn + wave * 32 + i * 8 + (lane >> 3)) * K_TOT
                        + (t + 1) * BK + (lane & 7) * 8;
                    gload_lds16(src, &Bs[cur ^ 1][0][0] + wave * 2048 + i * 512);
                }
            } else {
                const int brow = tid >> 1;
                #pragma unroll
                for (int i = 0; i < 4; ++i) {
                    const int ck = (tid & 1) * 4 + i;
                    const float4* s = reinterpret_cast<const float4*>(
                        W + (size_t)(bn + brow) * K_TOT + (t + 1) * BK + ck * 8);
                    float4 v0 = s[0], v1 = s[1];
                    bf16x8 b;
                    b[0] = (bf16_t)v0.x; b[1] = (bf16_t)v0.y; b[2] = (bf16_t)v0.z; b[3] = (bf16_t)v0.w;
                    b[4] = (bf16_t)v1.x; b[5] = (bf16_t)v1.y; b[6] = (bf16_t)v1.z; b[7] = (bf16_t)v1.w;
                    *reinterpret_cast<bf16x8*>(&Bs[cur ^ 1][brow][(ck ^ (brow & 7)) * 8]) = b;
                }
            }
        }
        __builtin_amdgcn_sched_barrier(0);   // pin: x-loads stay AFTER B gloads

        // ---- issue x(t+2) into pa[t&1] (x(t) consumed last step) ----
        if (t < NT - 2) {
            #pragma unroll
            for (int p = 0; p < 8; ++p)
                pa[t & 1][p] = *reinterpret_cast<const float4*>(
                    xb + (size_t)(srow + p * 16) * K_TOT + (t + 2) * BK + scol);
        }

        // ---- kk=0: frags + 16 MFMA ----
        {
            bf16x8 af[4], bfr[4];
            #pragma unroll
            for (int mi = 0; mi < 4; ++mi) {
                const int r = wm + mi * 16 + frow;
                const int c = fk ^ ((r & 7) << 3);
                af[mi] = *reinterpret_cast<bf16x8*>(&As[cur][r][c]);
            }
            #pragma unroll
            for (int nj = 0; nj < 4; ++nj) {
                const int r = wn + nj * 16 + frow;
                const int c = fk ^ ((r & 7) << 3);
                bfr[nj] = *reinterpret_cast<bf16x8*>(&Bs[cur][r][c]);
            }
            __builtin_amdgcn_s_setprio(1);
            #pragma unroll
            for (int mi = 0; mi < 4; ++mi)
                #pragma unroll
                for (int nj = 0; nj < 4; ++nj)
                    acc[mi][nj] = __builtin_amdgcn_mfma_f32_16x16x32_bf16(
                        af[mi], bfr[nj], acc[mi][nj], 0, 0, 0);
            __builtin_amdgcn_s_setprio(0);
        }

        // ---- cos(x(t+1)) -> As[cur^1]  (VALU fills the MFMA shadow) ----
        if (t < NT - 1) {
            #pragma unroll
            for (int p = 0; p < 8; ++p) {
                const int row = srow + p * 16;
                const int csw = scol ^ ((row & 7) << 3);
                bf16x4 a;
                a[0] = (bf16_t)__cosf(pa[(t + 1) & 1][p].x + p0);
                a[1] = (bf16_t)__cosf(pa[(t + 1) & 1][p].y + p1);
                a[2] = (bf16_t)__cosf(pa[(t + 1) & 1][p].z + p2);
                a[3] = (bf16_t)__cosf(pa[(t + 1) & 1][p].w + p3);
                *reinterpret_cast<bf16x4*>(&As[cur ^ 1][row][csw]) = a;
            }
        }

        // ---- kk=1: frags + 16 MFMA ----
        {
            bf16x8 af[4], bfr[4];
            #pragma unroll
            for (int mi = 0; mi < 4; ++mi) {
                const int r = wm + mi * 16 + frow;
                const int c = (32 + fk) ^ ((r & 7) << 3);
                af[mi] = *reinterpret_cast<bf16x8*>(&As[cur][r][c]);
            }
            #pragma unroll
            for (int nj = 0; nj < 4; ++nj) {
                const int r = wn + nj * 16 + frow;
                const int c = (32 + fk) ^ ((r & 7) << 3);
                bfr[nj] = *reinterpret_cast<bf16x8*>(&Bs[cur][r][c]);
            }
            __builtin_amdgcn_s_setprio(1);
            #pragma unroll
            for (int mi = 0; mi < 4; ++mi)
                #pragma unroll
                for (int nj = 0; nj < 4; ++nj)
                    acc[mi][nj] = __builtin_amdgcn_mfma_f32_16x16x32_bf16(
                        af[mi], bfr[nj], acc[mi][nj], 0, 0, 0);
            __builtin_amdgcn_s_setprio(0);
        }

        // ---- single barrier: B(t+1) drained (4 oldest), x(t+2) in flight ----
        if (t < NT - 2) {
            if constexpr (USE_WS)
                asm volatile("s_waitcnt vmcnt(8) lgkmcnt(0)\n\ts_barrier" ::: "memory");
            else
                asm volatile("s_waitcnt lgkmcnt(0)\n\ts_barrier" ::: "memory");
        } else if (t == NT - 2) {
            if constexpr (USE_WS)
                asm volatile("s_waitcnt vmcnt(0) lgkmcnt(0)\n\ts_barrier" ::: "memory");
            else
                asm volatile("s_waitcnt lgkmcnt(0)\n\ts_barrier" ::: "memory");
        }
        // t == NT-1: fall through to epilogue
    }

    // ---- epilogue: C/D map col=lane&15, row=(lane>>4)*4+i ----
    #pragma unroll
    for (int nj = 0; nj < 4; ++nj) {
        const int c  = bn + wn + nj * 16 + frow;
        const float bv = bias[c];
        #pragma unroll
        for (int mi = 0; mi < 4; ++mi) {
            const int r0 = bm + wm + mi * 16 + (lane >> 4) * 4;
            #pragma unroll
            for (int i = 0; i < 4; ++i)
                out[(size_t)(r0 + i) * N_TOT + c] = acc[mi][nj][i] + bv;
        }
    }
}

extern "C" void kernel_launch(void* const* d_in, const int* in_sizes, int n_in,
                              void* d_out, int out_size, void* d_ws, size_t ws_size,
                              hipStream_t stream) {
    const float* x    = (const float*)d_in[0];
    const float* phi  = (const float*)d_in[1];
    const float* W    = (const float*)d_in[2];
    const float* bias = (const float*)d_in[3];
    float* out = (float*)d_out;

    const int grid = (M_TOT / BM) * (N_TOT / BN);   // 2048
    const size_t ws_need = (size_t)N_TOT * K_TOT * sizeof(bf16_t);  // 512 KB

    if (ws_size >= ws_need) {
        bf16_t* Wws = (bf16_t*)d_ws;
        convert_W<<<(N_TOT * K_TOT / 8) / 256, 256, 0, stream>>>(W, Wws);
        qattn_fused_gemm<true><<<grid, 256, 0, stream>>>(x, phi, W, Wws, bias, out);
    } else {
        qattn_fused_gemm<false><<<grid, 256, 0, stream>>>(x, phi, W, nullptr, bias, out);
    }
}